// Round 2
// baseline (8135.403 us; speedup 1.0000x reference)
//
#include <hip/hip_runtime.h>
#include <math.h>

#define BB 4
#define SS 1024
#define HH 1024
#define LL 4
#define NHH 16
#define NKV 8
#define HD 64
#define FF 3072
#define WW 12
#define NEG_INF (-1e9f)

// ---------------------------------------------------------------------------
// Embedding gather: h[row, :] = embed[ids[row], :]
__global__ __launch_bounds__(256) void k_embed(const int* __restrict__ ids,
                                               const float* __restrict__ embed,
                                               float* __restrict__ h) {
    int row = blockIdx.x;
    int tid = threadIdx.x;                 // 256 threads, 4 floats each (H=1024)
    int id = ids[row];
    const float4* src = (const float4*)(embed + (size_t)id * HH);
    float4* dst = (float4*)(h + (size_t)row * HH);
    dst[tid] = src[tid];
}

// ---------------------------------------------------------------------------
// RMSNorm over H=1024: one block (256 thr) per row.
__global__ __launch_bounds__(256) void k_rms(const float* __restrict__ in,
                                             const float* __restrict__ w,
                                             float* __restrict__ out) {
    __shared__ float red[4];
    int row = blockIdx.x, tid = threadIdx.x;
    float4 v = ((const float4*)(in + (size_t)row * HH))[tid];
    float ss = v.x * v.x + v.y * v.y + v.z * v.z + v.w * v.w;
#pragma unroll
    for (int off = 1; off < 64; off <<= 1) ss += __shfl_xor(ss, off);
    if ((tid & 63) == 0) red[tid >> 6] = ss;
    __syncthreads();
    float tot = red[0] + red[1] + red[2] + red[3];
    float scale = rsqrtf(tot * (1.0f / HH) + 1e-6f);
    float4 wv = ((const float4*)w)[tid];
    float4 o;
    o.x = v.x * scale * wv.x;
    o.y = v.y * scale * wv.y;
    o.z = v.z * scale * wv.z;
    o.w = v.w * scale * wv.w;
    ((float4*)(out + (size_t)row * HH))[tid] = o;
}

// ---------------------------------------------------------------------------
// f32 GEMM core: C[bm:bm+128, bn:bn+128] (+)= A[M,K] @ B[K,N], row-major.
// 128x128 tile, BK=16, 256 threads, 8x8 microtile (split as 4+4 in each dim
// at +64 offsets so LDS reads are broadcast x 2-way -> conflict-free).
__device__ __forceinline__ void gemm_core(const float* __restrict__ A,
                                          const float* __restrict__ B,
                                          float* __restrict__ C,
                                          int N, int K, int bm, int bn, int epi) {
    __shared__ float As[16][128];   // As[k][m]
    __shared__ float Bs[16][128];   // Bs[k][n]
    int tid = threadIdx.x;
    int tx = tid & 15, ty = tid >> 4;          // compute thread coords
    int lm = tid >> 1, lk = (tid & 1) << 3;    // A-load: row lm, k-chunk lk (8)
    int kr = tid >> 4, nc = (tid & 15) << 3;   // B-load: k-row kr, col-chunk nc (8)

    float acc[8][8] = {};
    const float* Ap = A + (size_t)(bm + lm) * K + lk;
    const float* Bp = B + (size_t)kr * N + bn + nc;

    for (int k0 = 0; k0 < K; k0 += 16) {
        float4 a0 = *(const float4*)(Ap);
        float4 a1 = *(const float4*)(Ap + 4);
        float4 b0 = *(const float4*)(Bp);
        float4 b1 = *(const float4*)(Bp + 4);
        As[lk + 0][lm] = a0.x; As[lk + 1][lm] = a0.y;
        As[lk + 2][lm] = a0.z; As[lk + 3][lm] = a0.w;
        As[lk + 4][lm] = a1.x; As[lk + 5][lm] = a1.y;
        As[lk + 6][lm] = a1.z; As[lk + 7][lm] = a1.w;
        *(float4*)&Bs[kr][nc] = b0;
        *(float4*)&Bs[kr][nc + 4] = b1;
        __syncthreads();
#pragma unroll
        for (int kk = 0; kk < 16; ++kk) {
            float a8[8], b8[8];
            *(float4*)&a8[0] = *(const float4*)&As[kk][ty << 2];
            *(float4*)&a8[4] = *(const float4*)&As[kk][(ty << 2) + 64];
            *(float4*)&b8[0] = *(const float4*)&Bs[kk][tx << 2];
            *(float4*)&b8[4] = *(const float4*)&Bs[kk][(tx << 2) + 64];
#pragma unroll
            for (int i = 0; i < 8; ++i)
#pragma unroll
                for (int j = 0; j < 8; ++j)
                    acc[i][j] = fmaf(a8[i], b8[j], acc[i][j]);
        }
        __syncthreads();
        Ap += 16;
        Bp += (size_t)16 * N;
    }

#pragma unroll
    for (int i = 0; i < 8; ++i) {
        int row = bm + (ty << 2) + (i & 3) + ((i >> 2) << 6);
#pragma unroll
        for (int jh = 0; jh < 2; ++jh) {
            float4* dst = (float4*)(C + (size_t)row * N + bn + (tx << 2) + (jh << 6));
            float4 r;
            r.x = acc[i][jh * 4 + 0];
            r.y = acc[i][jh * 4 + 1];
            r.z = acc[i][jh * 4 + 2];
            r.w = acc[i][jh * 4 + 3];
            if (epi) {
                float4 o = *dst;
                r.x += o.x; r.y += o.y; r.z += o.z; r.w += o.w;
            }
            *dst = r;
        }
    }
}

// Generic GEMM: grid (N/128, M/128).
__global__ __launch_bounds__(256, 4) void k_gemm(const float* __restrict__ A,
                                                 const float* __restrict__ B,
                                                 float* __restrict__ C,
                                                 int N, int K, int epi) {
    gemm_core(A, B, C, N, K, blockIdx.y * 128, blockIdx.x * 128, epi);
}

// Fused QKV GEMM: grid (16, 32). n-tiles 0-7 -> Q, 8-11 -> K, 12-15 -> V.
__global__ __launch_bounds__(256, 4) void k_gemm_qkv(const float* __restrict__ x,
                                                     const float* __restrict__ wq,
                                                     const float* __restrict__ wk,
                                                     const float* __restrict__ wv,
                                                     float* __restrict__ q,
                                                     float* __restrict__ k,
                                                     float* __restrict__ v) {
    int nt = blockIdx.x;
    const float* B; float* C; int N, bn;
    if (nt < 8)       { B = wq; C = q; N = 1024; bn = nt * 128; }
    else if (nt < 12) { B = wk; C = k; N = 512;  bn = (nt - 8) * 128; }
    else              { B = wv; C = v; N = 512;  bn = (nt - 12) * 128; }
    gemm_core(x, B, C, N, 1024, blockIdx.y * 128, bn, 0);
}

// Fused gate+up GEMM: grid (48, 32). n-tiles 0-23 -> gate, 24-47 -> up.
__global__ __launch_bounds__(256, 4) void k_gemm_gu(const float* __restrict__ x,
                                                    const float* __restrict__ wg,
                                                    const float* __restrict__ wu,
                                                    float* __restrict__ g,
                                                    float* __restrict__ u) {
    int nt = blockIdx.x;
    const float* B = (nt < 24) ? wg : wu;
    float* C = (nt < 24) ? g : u;
    int bn = (nt < 24 ? nt : nt - 24) * 128;
    gemm_core(x, B, C, 3072, 1024, blockIdx.y * 128, bn, 0);
}

// ---------------------------------------------------------------------------
// Per-head RMSNorm (over HD=64) + RoPE. One wave per (row, head).
// qk layout: [B*S, nheads*HD]. pos = row % S. theta = 1e6.
__global__ __launch_bounds__(256) void k_qknorm_rope(float* __restrict__ qk,
                                                     const float* __restrict__ nw,
                                                     int nheads) {
    int tid = threadIdx.x;
    int w = tid >> 6, lane = tid & 63;
    int gid = blockIdx.x * 4 + w;          // wave id = row*nheads + head
    int row = gid / nheads;
    int pos = row & (SS - 1);
    size_t base = (size_t)gid * HD;
    float xv = qk[base + lane];
    float ss = xv * xv;
#pragma unroll
    for (int off = 1; off < 64; off <<= 1) ss += __shfl_xor(ss, off);
    float scale = rsqrtf(ss * (1.0f / HD) + 1e-6f);
    float xn = xv * scale * nw[lane];
    int j = lane & 31;
    float inv_freq = powf(1.0e6f, -(float)j * (1.0f / 32.0f));
    float f = (float)pos * inv_freq;
    float c = cosf(f), s = sinf(f);
    float partner = __shfl_xor(xn, 32);
    float rot = (lane < 32) ? -partner : partner;
    qk[base + lane] = xn * c + rot * s;
}

// ---------------------------------------------------------------------------
// Fused flash-style attention (non-causal full / sliding band +-12).
// Grid: (S/4, NH, B). Block: 256 = 4 waves; wave w handles q row q0+w.
// Within a tile: lane == key for scores, lane == dim for PV.
__global__ __launch_bounds__(256) void k_attn(const float* __restrict__ q,
                                              const float* __restrict__ k,
                                              const float* __restrict__ v,
                                              const int* __restrict__ amask,
                                              float* __restrict__ out,
                                              int sliding) {
    __shared__ float Ks[64][65];
    __shared__ float Vs[64][65];
    __shared__ float qs[4][64];
    __shared__ float ps[4][64];

    int b = blockIdx.z, h = blockIdx.y, q0 = blockIdx.x * 4;
    int kvh = h >> 1;  // NH/NKV = 2
    int tid = threadIdx.x;
    int w = tid >> 6, lane = tid & 63;
    int qrow = q0 + w;
    const float sm_scale = 0.125f;  // 1/sqrt(64)

    qs[w][lane] = q[((size_t)(b * SS + qrow) * NHH + h) * HD + lane];

    float m = -3.4e38f, l_sum = 0.0f, o = 0.0f;

    int t_lo = 0, t_hi = (SS >> 6) - 1;
    if (sliding) {
        int lo = q0 - WW; if (lo < 0) lo = 0;
        int hi = q0 + 3 + WW; if (hi > SS - 1) hi = SS - 1;
        t_lo = lo >> 6; t_hi = hi >> 6;
    }

    for (int t = t_lo; t <= t_hi; ++t) {
        int k0 = t << 6;
#pragma unroll
        for (int c = 0; c < 4; ++c) {
            int kr = (tid >> 4) + c * 16;
            int cg = (tid & 15) << 2;
            const float* kp = &k[((size_t)(b * SS + k0 + kr) * NKV + kvh) * HD + cg];
            const float* vp = &v[((size_t)(b * SS + k0 + kr) * NKV + kvh) * HD + cg];
#pragma unroll
            for (int e = 0; e < 4; ++e) {
                Ks[kr][cg + e] = kp[e];
                Vs[kr][cg + e] = vp[e];
            }
        }
        __syncthreads();

        // scores: lane = key index within tile
        float sc = 0.0f;
#pragma unroll
        for (int d = 0; d < 64; ++d) sc = fmaf(qs[w][d], Ks[lane][d], sc);
        int key = k0 + lane;
        float mval = (amask[b * SS + key] == 0) ? NEG_INF : 0.0f;
        if (sliding) {
            int dd = qrow - key; if (dd < 0) dd = -dd;
            if (dd > WW) mval = NEG_INF;
        }
        sc = sc * sm_scale + mval;

        float tmax = sc;
#pragma unroll
        for (int off = 1; off < 64; off <<= 1) tmax = fmaxf(tmax, __shfl_xor(tmax, off));
        float nm = fmaxf(m, tmax);
        float p = __expf(sc - nm);
        float tsum = p;
#pragma unroll
        for (int off = 1; off < 64; off <<= 1) tsum += __shfl_xor(tsum, off);
        float corr = __expf(m - nm);

        ps[w][lane] = p;
        __syncthreads();

        // PV: lane = output dim
        float acc = 0.0f;
#pragma unroll
        for (int jj = 0; jj < 64; ++jj) acc = fmaf(ps[w][jj], Vs[jj][lane], acc);
        o = o * corr + acc;
        l_sum = l_sum * corr + tsum;
        m = nm;
        __syncthreads();
    }

    out[((size_t)(b * SS + qrow) * NHH + h) * HD + lane] = o / l_sum;
}

// ---------------------------------------------------------------------------
// act = silu(gate) * up  (elementwise, float4)
__global__ __launch_bounds__(256) void k_silu_mul(const float* __restrict__ gate,
                                                  const float* __restrict__ up,
                                                  float* __restrict__ act) {
    int i = blockIdx.x * 256 + threadIdx.x;
    float4 g = ((const float4*)gate)[i];
    float4 u = ((const float4*)up)[i];
    float4 r;
    r.x = g.x / (1.0f + __expf(-g.x)) * u.x;
    r.y = g.y / (1.0f + __expf(-g.y)) * u.y;
    r.z = g.z / (1.0f + __expf(-g.z)) * u.z;
    r.w = g.w / (1.0f + __expf(-g.w)) * u.w;
    ((float4*)act)[i] = r;
}

// ---------------------------------------------------------------------------
extern "C" void kernel_launch(void* const* d_in, const int* in_sizes, int n_in,
                              void* d_out, int out_size, void* d_ws, size_t ws_size,
                              hipStream_t stream) {
    const int* input_ids = (const int*)d_in[0];
    const int* amask     = (const int*)d_in[1];
    const float* embed   = (const float*)d_in[2];
    const float* wq      = (const float*)d_in[3];
    const float* wk      = (const float*)d_in[4];
    const float* wv      = (const float*)d_in[5];
    const float* wo      = (const float*)d_in[6];
    const float* qnw     = (const float*)d_in[7];
    const float* knw     = (const float*)d_in[8];
    const float* ln1     = (const float*)d_in[9];
    const float* ln2     = (const float*)d_in[10];
    const float* wg      = (const float*)d_in[11];
    const float* wu      = (const float*)d_in[12];
    const float* wd      = (const float*)d_in[13];
    const float* fnorm   = (const float*)d_in[14];
    float* out = (float*)d_out;

    const int ROWS = BB * SS;               // 4096
    float* h    = (float*)d_ws;             // [4096,1024]
    float* x    = h    + (size_t)ROWS * HH; // [4096,1024] (also attn out)
    float* qb   = x    + (size_t)ROWS * HH; // [4096,16*64]
    float* kb   = qb   + (size_t)ROWS * HH; // [4096,8*64]
    float* vb   = kb   + (size_t)ROWS * (NKV * HD);
    float* gate = vb   + (size_t)ROWS * (NKV * HD); // [4096,3072]
    float* up   = gate + (size_t)ROWS * FF;         // [4096,3072]

    k_embed<<<ROWS, 256, 0, stream>>>(input_ids, embed, h);

    for (int l = 0; l < LL; ++l) {
        const float* wq_l = wq + (size_t)l * HH * (NHH * HD);
        const float* wk_l = wk + (size_t)l * HH * (NKV * HD);
        const float* wv_l = wv + (size_t)l * HH * (NKV * HD);
        const float* wo_l = wo + (size_t)l * (NHH * HD) * HH;
        const float* wg_l = wg + (size_t)l * HH * FF;
        const float* wu_l = wu + (size_t)l * HH * FF;
        const float* wd_l = wd + (size_t)l * FF * HH;

        k_rms<<<ROWS, 256, 0, stream>>>(h, ln1 + l * HH, x);

        k_gemm_qkv<<<dim3(16, 32), 256, 0, stream>>>(x, wq_l, wk_l, wv_l, qb, kb, vb);

        k_qknorm_rope<<<ROWS * NHH / 4, 256, 0, stream>>>(qb, qnw + l * HD, NHH);
        k_qknorm_rope<<<ROWS * NKV / 4, 256, 0, stream>>>(kb, knw + l * HD, NKV);

        k_attn<<<dim3(SS / 4, NHH, BB), 256, 0, stream>>>(qb, kb, vb, amask, x, l & 1);

        k_gemm<<<dim3(8, 32), 256, 0, stream>>>(x, wo_l, h, HH, NHH * HD, 1);

        k_rms<<<ROWS, 256, 0, stream>>>(h, ln2 + l * HH, x);

        k_gemm_gu<<<dim3(48, 32), 256, 0, stream>>>(x, wg_l, wu_l, gate, up);

        k_silu_mul<<<ROWS * FF / 4 / 256, 256, 0, stream>>>(gate, up, gate);

        k_gemm<<<dim3(8, 32), 256, 0, stream>>>(gate, wd_l, h, HH, FF, 1);
    }

    k_rms<<<ROWS, 256, 0, stream>>>(h, fnorm, out);
}

// Round 3
// 3465.190 us; speedup vs baseline: 2.3478x; 2.3478x over previous
//
#include <hip/hip_runtime.h>
#include <math.h>

#define BB 4
#define SS 1024
#define HH 1024
#define LL 4
#define NHH 16
#define NKV 8
#define HD 64
#define FF 3072
#define WW 12
#define NEG_INF (-1e9f)

typedef __attribute__((ext_vector_type(8))) short bf16x8;
typedef __attribute__((ext_vector_type(4))) float f32x4;
typedef __attribute__((ext_vector_type(8))) unsigned short u16x8;

__device__ __forceinline__ unsigned short f2bf(float f) {
    union { float f; unsigned int u; } v; v.f = f;
    unsigned int r = (v.u + 0x7fffu + ((v.u >> 16) & 1u)) >> 16;
    return (unsigned short)r;
}
__device__ __forceinline__ float bf2f(unsigned short u) {
    union { unsigned int u; float f; } v; v.u = ((unsigned int)u) << 16;
    return v.f;
}
__device__ __forceinline__ void gll16(const void* g, void* l) {
    __builtin_amdgcn_global_load_lds((const __attribute__((address_space(1))) void*)g,
                                     (__attribute__((address_space(3))) void*)l, 16, 0, 0);
}

// ---------------------------------------------------------------------------
__global__ __launch_bounds__(256) void k_embed(const int* __restrict__ ids,
                                               const float* __restrict__ embed,
                                               float* __restrict__ h) {
    int row = blockIdx.x, tid = threadIdx.x;
    int id = ids[row];
    ((float4*)(h + (size_t)row * HH))[tid] = ((const float4*)(embed + (size_t)id * HH))[tid];
}

// ---------------------------------------------------------------------------
// RMSNorm over H=1024, f32 out (final norm)
__global__ __launch_bounds__(256) void k_rms(const float* __restrict__ in,
                                             const float* __restrict__ w,
                                             float* __restrict__ out) {
    __shared__ float red[4];
    int row = blockIdx.x, tid = threadIdx.x;
    float4 v = ((const float4*)(in + (size_t)row * HH))[tid];
    float ss = v.x * v.x + v.y * v.y + v.z * v.z + v.w * v.w;
#pragma unroll
    for (int off = 1; off < 64; off <<= 1) ss += __shfl_xor(ss, off);
    if ((tid & 63) == 0) red[tid >> 6] = ss;
    __syncthreads();
    float tot = red[0] + red[1] + red[2] + red[3];
    float scale = rsqrtf(tot * (1.0f / HH) + 1e-6f);
    float4 wv = ((const float4*)w)[tid];
    float4 o;
    o.x = v.x * scale * wv.x; o.y = v.y * scale * wv.y;
    o.z = v.z * scale * wv.z; o.w = v.w * scale * wv.w;
    ((float4*)(out + (size_t)row * HH))[tid] = o;
}

// RMSNorm, bf16 out (feeds MFMA GEMMs)
__global__ __launch_bounds__(256) void k_rms_bf16(const float* __restrict__ in,
                                                  const float* __restrict__ w,
                                                  unsigned short* __restrict__ out) {
    __shared__ float red[4];
    int row = blockIdx.x, tid = threadIdx.x;
    float4 v = ((const float4*)(in + (size_t)row * HH))[tid];
    float ss = v.x * v.x + v.y * v.y + v.z * v.z + v.w * v.w;
#pragma unroll
    for (int off = 1; off < 64; off <<= 1) ss += __shfl_xor(ss, off);
    if ((tid & 63) == 0) red[tid >> 6] = ss;
    __syncthreads();
    float tot = red[0] + red[1] + red[2] + red[3];
    float scale = rsqrtf(tot * (1.0f / HH) + 1e-6f);
    float4 wv = ((const float4*)w)[tid];
    ushort4 o;
    o.x = f2bf(v.x * scale * wv.x); o.y = f2bf(v.y * scale * wv.y);
    o.z = f2bf(v.z * scale * wv.z); o.w = f2bf(v.w * scale * wv.w);
    *(ushort4*)&out[(size_t)row * HH + tid * 4] = o;
}

// ---------------------------------------------------------------------------
// flat f32 -> bf16 cast (8 elems/thread)
__global__ __launch_bounds__(256) void k_cast(const float* __restrict__ in,
                                              unsigned short* __restrict__ out) {
    int i = blockIdx.x * 256 + threadIdx.x;
    float4 a = ((const float4*)in)[i * 2];
    float4 b = ((const float4*)in)[i * 2 + 1];
    u16x8 o;
    o[0] = f2bf(a.x); o[1] = f2bf(a.y); o[2] = f2bf(a.z); o[3] = f2bf(a.w);
    o[4] = f2bf(b.x); o[5] = f2bf(b.y); o[6] = f2bf(b.z); o[7] = f2bf(b.w);
    ((u16x8*)out)[i] = o;
}

// ---------------------------------------------------------------------------
// cast + transpose: W [K][N] f32 -> Wt [N][K] bf16. grid (N/64, K/64).
__global__ __launch_bounds__(256) void k_cast_t(const float* __restrict__ W,
                                                unsigned short* __restrict__ Wt,
                                                int N, int K) {
    __shared__ float t[64][65];
    int n0 = blockIdx.x * 64, k0 = blockIdx.y * 64;
    int tid = threadIdx.x;
    int r = tid >> 4;            // 0..15
    int c4 = (tid & 15) * 4;     // 0..60
#pragma unroll
    for (int e = 0; e < 4; ++e) {
        int kk = r + e * 16;
        float4 vv = *(const float4*)&W[(size_t)(k0 + kk) * N + n0 + c4];
        t[c4 + 0][kk] = vv.x;
        t[c4 + 1][kk] = vv.y;
        t[c4 + 2][kk] = vv.z;
        t[c4 + 3][kk] = vv.w;
    }
    __syncthreads();
#pragma unroll
    for (int e = 0; e < 4; ++e) {
        int nn = r + e * 16;
        ushort4 o;
        o.x = f2bf(t[nn][c4 + 0]);
        o.y = f2bf(t[nn][c4 + 1]);
        o.z = f2bf(t[nn][c4 + 2]);
        o.w = f2bf(t[nn][c4 + 3]);
        *(ushort4*)&Wt[(size_t)(n0 + nn) * K + k0 + c4] = o;
    }
}

// ---------------------------------------------------------------------------
// bf16 MFMA GEMM core (m97 structure): C[128x128] (+)= A[M][K] @ Bt[N][K]^T.
// 256 threads = 4 waves, each wave a 64x64 quadrant, 4x4 frags of 16x16x32.
// EPI: 0 = store f32, 1 = += f32, 2 = store bf16.
template <int EPI>
__device__ __forceinline__ void mgemm_core(const unsigned short* __restrict__ A,
                                           const unsigned short* __restrict__ Bt,
                                           void* __restrict__ Cv,
                                           int N, int K, int bm, int bn) {
    __shared__ unsigned short As[128 * 32];  // [m][k], 8KB
    __shared__ unsigned short Bs[128 * 32];  // [n][k], 8KB
    int tid = threadIdx.x;
    int w = tid >> 6, l = tid & 63;
    int wr = (w >> 1) * 64, wc = (w & 1) * 64;

    f32x4 acc[4][4] = {};

    for (int k0 = 0; k0 < K; k0 += 32) {
        __syncthreads();
#pragma unroll
        for (int i = 0; i < 2; ++i) {
            int cb = i * 256 + w * 64;   // wave-uniform chunk base
            int c = cb + l;
            const unsigned short* ga = A + (size_t)(bm + (c >> 2)) * K + k0 + (c & 3) * 8;
            const unsigned short* gb = Bt + (size_t)(bn + (c >> 2)) * K + k0 + (c & 3) * 8;
            gll16(ga, As + cb * 8);
            gll16(gb, Bs + cb * 8);
        }
        __syncthreads();

        bf16x8 af[4], bfr[4];
#pragma unroll
        for (int i = 0; i < 4; ++i) {
            int m = wr + i * 16 + (l & 15);
            af[i] = *(const bf16x8*)&As[m * 32 + (l >> 4) * 8];
            int n = wc + i * 16 + (l & 15);
            bfr[i] = *(const bf16x8*)&Bs[n * 32 + (l >> 4) * 8];
        }
#pragma unroll
        for (int i = 0; i < 4; ++i)
#pragma unroll
            for (int j = 0; j < 4; ++j)
                acc[i][j] = __builtin_amdgcn_mfma_f32_16x16x32_bf16(af[i], bfr[j], acc[i][j], 0, 0, 0);
    }

#pragma unroll
    for (int i = 0; i < 4; ++i) {
        int rbase = bm + wr + i * 16 + (l >> 4) * 4;
#pragma unroll
        for (int j = 0; j < 4; ++j) {
            int col = bn + wc + j * 16 + (l & 15);
#pragma unroll
            for (int r = 0; r < 4; ++r) {
                size_t off = (size_t)(rbase + r) * N + col;
                if (EPI == 0) ((float*)Cv)[off] = acc[i][j][r];
                else if (EPI == 1) ((float*)Cv)[off] += acc[i][j][r];
                else ((unsigned short*)Cv)[off] = f2bf(acc[i][j][r]);
            }
        }
    }
}

template <int EPI>
__global__ __launch_bounds__(256) void k_mgemm(const unsigned short* __restrict__ A,
                                               const unsigned short* __restrict__ Bt,
                                               void* __restrict__ C,
                                               int N, int K) {
    mgemm_core<EPI>(A, Bt, C, N, K, blockIdx.y * 128, blockIdx.x * 128);
}

// QKV fused: grid (16, 32). nt 0-7 -> Q (N=1024), 8-11 -> K (512), 12-15 -> V.
__global__ __launch_bounds__(256) void k_mgemm_qkv(const unsigned short* __restrict__ A,
                                                   const unsigned short* __restrict__ wqt,
                                                   const unsigned short* __restrict__ wkt,
                                                   const unsigned short* __restrict__ wvt,
                                                   float* __restrict__ q,
                                                   float* __restrict__ k,
                                                   float* __restrict__ v) {
    int nt = blockIdx.x;
    const unsigned short* Bt; float* C; int N, bn;
    if (nt < 8)       { Bt = wqt; C = q; N = 1024; bn = nt * 128; }
    else if (nt < 12) { Bt = wkt; C = k; N = 512;  bn = (nt - 8) * 128; }
    else              { Bt = wvt; C = v; N = 512;  bn = (nt - 12) * 128; }
    mgemm_core<0>(A, Bt, C, N, 1024, blockIdx.y * 128, bn);
}

// gate+up fused, bf16 out: grid (48, 32).
__global__ __launch_bounds__(256) void k_mgemm_gu(const unsigned short* __restrict__ A,
                                                  const unsigned short* __restrict__ wgt,
                                                  const unsigned short* __restrict__ wut,
                                                  unsigned short* __restrict__ g,
                                                  unsigned short* __restrict__ u) {
    int nt = blockIdx.x;
    const unsigned short* Bt = (nt < 24) ? wgt : wut;
    unsigned short* C = (nt < 24) ? g : u;
    int bn = (nt < 24 ? nt : nt - 24) * 128;
    mgemm_core<2>(A, Bt, C, 3072, 1024, blockIdx.y * 128, bn);
}

// ---------------------------------------------------------------------------
// Per-head RMSNorm (HD=64) + RoPE, f32 in-place.
__global__ __launch_bounds__(256) void k_qknorm_rope(float* __restrict__ qk,
                                                     const float* __restrict__ nw,
                                                     int nheads) {
    int tid = threadIdx.x;
    int w = tid >> 6, lane = tid & 63;
    int gid = blockIdx.x * 4 + w;
    int row = gid / nheads;
    int pos = row & (SS - 1);
    size_t base = (size_t)gid * HD;
    float xv = qk[base + lane];
    float ss = xv * xv;
#pragma unroll
    for (int off = 1; off < 64; off <<= 1) ss += __shfl_xor(ss, off);
    float scale = rsqrtf(ss * (1.0f / HD) + 1e-6f);
    float xn = xv * scale * nw[lane];
    int j = lane & 31;
    float inv_freq = powf(1.0e6f, -(float)j * (1.0f / 32.0f));
    float f = (float)pos * inv_freq;
    float c = cosf(f), s = sinf(f);
    float partner = __shfl_xor(xn, 32);
    float rot = (lane < 32) ? -partner : partner;
    qk[base + lane] = xn * c + rot * s;
}

// ---------------------------------------------------------------------------
// Flash-style f32 attention, vectorized LDS reads.
__global__ __launch_bounds__(256) void k_attn(const float* __restrict__ q,
                                              const float* __restrict__ k,
                                              const float* __restrict__ v,
                                              const int* __restrict__ amask,
                                              float* __restrict__ out,
                                              int sliding) {
    __shared__ float Ks[64][68];
    __shared__ float Vs[64][68];
    __shared__ float qs[4][64];
    __shared__ float ps[4][64];

    int b = blockIdx.z, h = blockIdx.y, q0 = blockIdx.x * 4;
    int kvh = h >> 1;
    int tid = threadIdx.x;
    int w = tid >> 6, lane = tid & 63;
    int qrow = q0 + w;
    const float sm_scale = 0.125f;

    qs[w][lane] = q[((size_t)(b * SS + qrow) * NHH + h) * HD + lane];

    float m = -3.4e38f, l_sum = 0.0f, o = 0.0f;

    int t_lo = 0, t_hi = (SS >> 6) - 1;
    if (sliding) {
        int lo = q0 - WW; if (lo < 0) lo = 0;
        int hi = q0 + 3 + WW; if (hi > SS - 1) hi = SS - 1;
        t_lo = lo >> 6; t_hi = hi >> 6;
    }

    for (int t = t_lo; t <= t_hi; ++t) {
        int k0 = t << 6;
#pragma unroll
        for (int c = 0; c < 4; ++c) {
            int kr = (tid >> 4) + c * 16;
            int cg = (tid & 15) << 2;
            const float* kp = &k[((size_t)(b * SS + k0 + kr) * NKV + kvh) * HD + cg];
            const float* vp = &v[((size_t)(b * SS + k0 + kr) * NKV + kvh) * HD + cg];
#pragma unroll
            for (int e = 0; e < 4; ++e) {
                Ks[kr][cg + e] = kp[e];
                Vs[kr][cg + e] = vp[e];
            }
        }
        __syncthreads();

        float sc = 0.0f;
#pragma unroll
        for (int d4 = 0; d4 < 16; ++d4) {
            float4 kk = *(const float4*)&Ks[lane][d4 * 4];
            float4 qv = *(const float4*)&qs[w][d4 * 4];
            sc = fmaf(qv.x, kk.x, sc);
            sc = fmaf(qv.y, kk.y, sc);
            sc = fmaf(qv.z, kk.z, sc);
            sc = fmaf(qv.w, kk.w, sc);
        }
        int key = k0 + lane;
        float mval = (amask[b * SS + key] == 0) ? NEG_INF : 0.0f;
        if (sliding) {
            int dd = qrow - key; if (dd < 0) dd = -dd;
            if (dd > WW) mval = NEG_INF;
        }
        sc = sc * sm_scale + mval;

        float tmax = sc;
#pragma unroll
        for (int off = 1; off < 64; off <<= 1) tmax = fmaxf(tmax, __shfl_xor(tmax, off));
        float nm = fmaxf(m, tmax);
        float p = __expf(sc - nm);
        float tsum = p;
#pragma unroll
        for (int off = 1; off < 64; off <<= 1) tsum += __shfl_xor(tsum, off);
        float corr = __expf(m - nm);

        ps[w][lane] = p;
        __syncthreads();

        float acc = 0.0f;
#pragma unroll
        for (int c = 0; c < 16; ++c) {
            float4 pp = *(const float4*)&ps[w][c * 4];
            acc = fmaf(pp.x, Vs[c * 4 + 0][lane], acc);
            acc = fmaf(pp.y, Vs[c * 4 + 1][lane], acc);
            acc = fmaf(pp.z, Vs[c * 4 + 2][lane], acc);
            acc = fmaf(pp.w, Vs[c * 4 + 3][lane], acc);
        }
        o = o * corr + acc;
        l_sum = l_sum * corr + tsum;
        m = nm;
        __syncthreads();
    }

    out[((size_t)(b * SS + qrow) * NHH + h) * HD + lane] = o / l_sum;
}

// ---------------------------------------------------------------------------
// g = silu(g) * u   (bf16 in/out, 8 elems/thread)
__global__ __launch_bounds__(256) void k_silu_bf16(unsigned short* __restrict__ g,
                                                   const unsigned short* __restrict__ u) {
    int i = blockIdx.x * 256 + threadIdx.x;
    u16x8 gv = ((const u16x8*)g)[i];
    u16x8 uv = ((const u16x8*)u)[i];
    u16x8 o;
#pragma unroll
    for (int j = 0; j < 8; ++j) {
        float gf = bf2f(gv[j]), uf = bf2f(uv[j]);
        o[j] = f2bf(gf / (1.0f + __expf(-gf)) * uf);
    }
    ((u16x8*)g)[i] = o;
}

// ---------------------------------------------------------------------------
extern "C" void kernel_launch(void* const* d_in, const int* in_sizes, int n_in,
                              void* d_out, int out_size, void* d_ws, size_t ws_size,
                              hipStream_t stream) {
    const int* input_ids = (const int*)d_in[0];
    const int* amask     = (const int*)d_in[1];
    const float* embed   = (const float*)d_in[2];
    const float* wq      = (const float*)d_in[3];
    const float* wk      = (const float*)d_in[4];
    const float* wv      = (const float*)d_in[5];
    const float* wo      = (const float*)d_in[6];
    const float* qnw     = (const float*)d_in[7];
    const float* knw     = (const float*)d_in[8];
    const float* ln1     = (const float*)d_in[9];
    const float* ln2     = (const float*)d_in[10];
    const float* wg      = (const float*)d_in[11];
    const float* wu      = (const float*)d_in[12];
    const float* wd      = (const float*)d_in[13];
    const float* fnorm   = (const float*)d_in[14];
    float* out = (float*)d_out;

    const int ROWS = BB * SS;  // 4096
    float* h  = (float*)d_ws;                      // [4096,1024] f32
    float* x  = h + (size_t)ROWS * HH;             // [4096,1024] f32 (attn out)
    float* qb = x + (size_t)ROWS * HH;             // [4096,1024] f32
    float* kb = qb + (size_t)ROWS * HH;            // [4096,512]  f32
    float* vb = kb + (size_t)ROWS * (NKV * HD);    // [4096,512]  f32
    unsigned short* xb  = (unsigned short*)(vb + (size_t)ROWS * (NKV * HD)); // [4096,1024] bf16
    unsigned short* gbf = xb + (size_t)ROWS * HH;          // [4096,3072] bf16
    unsigned short* ubf = gbf + (size_t)ROWS * FF;         // [4096,3072] bf16
    unsigned short* wbf = ubf + (size_t)ROWS * FF;         // 12.58M bf16 (per-layer weights^T)

    const size_t OQ = 0, OK_ = 1048576, OV = 1572864, OO = 2097152,
                 OG = 3145728, OU = 6291456, OD = 9437184;

    k_embed<<<ROWS, 256, 0, stream>>>(input_ids, embed, h);

    for (int l = 0; l < LL; ++l) {
        const float* wq_l = wq + (size_t)l * HH * (NHH * HD);
        const float* wk_l = wk + (size_t)l * HH * (NKV * HD);
        const float* wv_l = wv + (size_t)l * HH * (NKV * HD);
        const float* wo_l = wo + (size_t)l * (NHH * HD) * HH;
        const float* wg_l = wg + (size_t)l * HH * FF;
        const float* wu_l = wu + (size_t)l * HH * FF;
        const float* wd_l = wd + (size_t)l * FF * HH;

        // weight cast+transpose into wbf (bf16, [N][K])
        k_cast_t<<<dim3(16, 16), 256, 0, stream>>>(wq_l, wbf + OQ, 1024, 1024);
        k_cast_t<<<dim3(8, 16),  256, 0, stream>>>(wk_l, wbf + OK_, 512, 1024);
        k_cast_t<<<dim3(8, 16),  256, 0, stream>>>(wv_l, wbf + OV, 512, 1024);
        k_cast_t<<<dim3(16, 16), 256, 0, stream>>>(wo_l, wbf + OO, 1024, 1024);
        k_cast_t<<<dim3(48, 16), 256, 0, stream>>>(wg_l, wbf + OG, 3072, 1024);
        k_cast_t<<<dim3(48, 16), 256, 0, stream>>>(wu_l, wbf + OU, 3072, 1024);
        k_cast_t<<<dim3(16, 48), 256, 0, stream>>>(wd_l, wbf + OD, 1024, 3072);

        k_rms_bf16<<<ROWS, 256, 0, stream>>>(h, ln1 + l * HH, xb);

        k_mgemm_qkv<<<dim3(16, 32), 256, 0, stream>>>(xb, wbf + OQ, wbf + OK_, wbf + OV,
                                                      qb, kb, vb);

        k_qknorm_rope<<<ROWS * NHH / 4, 256, 0, stream>>>(qb, qnw + l * HD, NHH);
        k_qknorm_rope<<<ROWS * NKV / 4, 256, 0, stream>>>(kb, knw + l * HD, NKV);

        k_attn<<<dim3(SS / 4, NHH, BB), 256, 0, stream>>>(qb, kb, vb, amask, x, l & 1);

        k_cast<<<ROWS * HH / 8 / 256, 256, 0, stream>>>(x, xb);
        k_mgemm<1><<<dim3(8, 32), 256, 0, stream>>>(xb, wbf + OO, h, 1024, 1024);

        k_rms_bf16<<<ROWS, 256, 0, stream>>>(h, ln2 + l * HH, xb);

        k_mgemm_gu<<<dim3(48, 32), 256, 0, stream>>>(xb, wbf + OG, wbf + OU, gbf, ubf);

        k_silu_bf16<<<ROWS * FF / 8 / 256, 256, 0, stream>>>(gbf, ubf);

        k_mgemm<1><<<dim3(8, 32), 256, 0, stream>>>(gbf, wbf + OD, h, 1024, 3072);
    }

    k_rms<<<ROWS, 256, 0, stream>>>(h, fnorm, out);
}

// Round 4
// 1570.724 us; speedup vs baseline: 5.1794x; 2.2061x over previous
//
#include <hip/hip_runtime.h>
#include <math.h>

#define BB 4
#define SS 1024
#define HH 1024
#define LL 4
#define NHH 16
#define NKV 8
#define HD 64
#define FF 3072
#define WW 12
#define NEG_INF (-1e9f)

typedef __attribute__((ext_vector_type(8))) short bf16x8;
typedef __attribute__((ext_vector_type(4))) float f32x4;
typedef __attribute__((ext_vector_type(16))) float f32x16;
typedef __attribute__((ext_vector_type(8))) unsigned short u16x8;

__device__ __forceinline__ unsigned short f2bf(float f) {
    union { float f; unsigned int u; } v; v.f = f;
    unsigned int r = (v.u + 0x7fffu + ((v.u >> 16) & 1u)) >> 16;
    return (unsigned short)r;
}
__device__ __forceinline__ float bf2f(unsigned short u) {
    union { unsigned int u; float f; } v; v.u = ((unsigned int)u) << 16;
    return v.f;
}
__device__ __forceinline__ unsigned int pkbf(float lo, float hi) {
    return (unsigned int)f2bf(lo) | ((unsigned int)f2bf(hi) << 16);
}
__device__ __forceinline__ void gll16(const void* g, void* l) {
    __builtin_amdgcn_global_load_lds((const __attribute__((address_space(1))) void*)g,
                                     (__attribute__((address_space(3))) void*)l, 16, 0, 0);
}

// ---------------------------------------------------------------------------
__global__ __launch_bounds__(256) void k_embed(const int* __restrict__ ids,
                                               const float* __restrict__ embed,
                                               float* __restrict__ h) {
    int row = blockIdx.x, tid = threadIdx.x;
    int id = ids[row];
    ((float4*)(h + (size_t)row * HH))[tid] = ((const float4*)(embed + (size_t)id * HH))[tid];
}

// ---------------------------------------------------------------------------
__global__ __launch_bounds__(256) void k_rms(const float* __restrict__ in,
                                             const float* __restrict__ w,
                                             float* __restrict__ out) {
    __shared__ float red[4];
    int row = blockIdx.x, tid = threadIdx.x;
    float4 v = ((const float4*)(in + (size_t)row * HH))[tid];
    float ss = v.x * v.x + v.y * v.y + v.z * v.z + v.w * v.w;
#pragma unroll
    for (int off = 1; off < 64; off <<= 1) ss += __shfl_xor(ss, off);
    if ((tid & 63) == 0) red[tid >> 6] = ss;
    __syncthreads();
    float tot = red[0] + red[1] + red[2] + red[3];
    float scale = rsqrtf(tot * (1.0f / HH) + 1e-6f);
    float4 wv = ((const float4*)w)[tid];
    float4 o;
    o.x = v.x * scale * wv.x; o.y = v.y * scale * wv.y;
    o.z = v.z * scale * wv.z; o.w = v.w * scale * wv.w;
    ((float4*)(out + (size_t)row * HH))[tid] = o;
}

__global__ __launch_bounds__(256) void k_rms_bf16(const float* __restrict__ in,
                                                  const float* __restrict__ w,
                                                  unsigned short* __restrict__ out) {
    __shared__ float red[4];
    int row = blockIdx.x, tid = threadIdx.x;
    float4 v = ((const float4*)(in + (size_t)row * HH))[tid];
    float ss = v.x * v.x + v.y * v.y + v.z * v.z + v.w * v.w;
#pragma unroll
    for (int off = 1; off < 64; off <<= 1) ss += __shfl_xor(ss, off);
    if ((tid & 63) == 0) red[tid >> 6] = ss;
    __syncthreads();
    float tot = red[0] + red[1] + red[2] + red[3];
    float scale = rsqrtf(tot * (1.0f / HH) + 1e-6f);
    float4 wv = ((const float4*)w)[tid];
    ushort4 o;
    o.x = f2bf(v.x * scale * wv.x); o.y = f2bf(v.y * scale * wv.y);
    o.z = f2bf(v.z * scale * wv.z); o.w = f2bf(v.w * scale * wv.w);
    *(ushort4*)&out[(size_t)row * HH + tid * 4] = o;
}

// ---------------------------------------------------------------------------
// cast + transpose: W [K][N] f32 -> Wt [N][K] bf16. grid (N/64, K/64).
__global__ __launch_bounds__(256) void k_cast_t(const float* __restrict__ W,
                                                unsigned short* __restrict__ Wt,
                                                int N, int K) {
    __shared__ float t[64][65];
    int n0 = blockIdx.x * 64, k0 = blockIdx.y * 64;
    int tid = threadIdx.x;
    int r = tid >> 4;
    int c4 = (tid & 15) * 4;
#pragma unroll
    for (int e = 0; e < 4; ++e) {
        int kk = r + e * 16;
        float4 vv = *(const float4*)&W[(size_t)(k0 + kk) * N + n0 + c4];
        t[c4 + 0][kk] = vv.x;
        t[c4 + 1][kk] = vv.y;
        t[c4 + 2][kk] = vv.z;
        t[c4 + 3][kk] = vv.w;
    }
    __syncthreads();
#pragma unroll
    for (int e = 0; e < 4; ++e) {
        int nn = r + e * 16;
        ushort4 o;
        o.x = f2bf(t[nn][c4 + 0]);
        o.y = f2bf(t[nn][c4 + 1]);
        o.z = f2bf(t[nn][c4 + 2]);
        o.w = f2bf(t[nn][c4 + 3]);
        *(ushort4*)&Wt[(size_t)(n0 + nn) * K + k0 + c4] = o;
    }
}

// ---------------------------------------------------------------------------
// bf16 MFMA GEMM (m97 structure). EPI: 0 = store f32, 1 = += f32, 2 = store bf16.
template <int EPI>
__device__ __forceinline__ void mgemm_core(const unsigned short* __restrict__ A,
                                           const unsigned short* __restrict__ Bt,
                                           void* __restrict__ Cv,
                                           int N, int K, int bm, int bn) {
    __shared__ unsigned short As[128 * 32];
    __shared__ unsigned short Bs[128 * 32];
    int tid = threadIdx.x;
    int w = tid >> 6, l = tid & 63;
    int wr = (w >> 1) * 64, wc = (w & 1) * 64;

    f32x4 acc[4][4] = {};

    for (int k0 = 0; k0 < K; k0 += 32) {
        __syncthreads();
#pragma unroll
        for (int i = 0; i < 2; ++i) {
            int cb = i * 256 + w * 64;
            int c = cb + l;
            const unsigned short* ga = A + (size_t)(bm + (c >> 2)) * K + k0 + (c & 3) * 8;
            const unsigned short* gb = Bt + (size_t)(bn + (c >> 2)) * K + k0 + (c & 3) * 8;
            gll16(ga, As + cb * 8);
            gll16(gb, Bs + cb * 8);
        }
        __syncthreads();

        bf16x8 af[4], bfr[4];
#pragma unroll
        for (int i = 0; i < 4; ++i) {
            int m = wr + i * 16 + (l & 15);
            af[i] = *(const bf16x8*)&As[m * 32 + (l >> 4) * 8];
            int n = wc + i * 16 + (l & 15);
            bfr[i] = *(const bf16x8*)&Bs[n * 32 + (l >> 4) * 8];
        }
#pragma unroll
        for (int i = 0; i < 4; ++i)
#pragma unroll
            for (int j = 0; j < 4; ++j)
                acc[i][j] = __builtin_amdgcn_mfma_f32_16x16x32_bf16(af[i], bfr[j], acc[i][j], 0, 0, 0);
    }

#pragma unroll
    for (int i = 0; i < 4; ++i) {
        int rbase = bm + wr + i * 16 + (l >> 4) * 4;
#pragma unroll
        for (int j = 0; j < 4; ++j) {
            int col = bn + wc + j * 16 + (l & 15);
#pragma unroll
            for (int r = 0; r < 4; ++r) {
                size_t off = (size_t)(rbase + r) * N + col;
                if (EPI == 0) ((float*)Cv)[off] = acc[i][j][r];
                else if (EPI == 1) ((float*)Cv)[off] += acc[i][j][r];
                else ((unsigned short*)Cv)[off] = f2bf(acc[i][j][r]);
            }
        }
    }
}

template <int EPI>
__global__ __launch_bounds__(256) void k_mgemm(const unsigned short* __restrict__ A,
                                               const unsigned short* __restrict__ Bt,
                                               void* __restrict__ C,
                                               int N, int K) {
    mgemm_core<EPI>(A, Bt, C, N, K, blockIdx.y * 128, blockIdx.x * 128);
}

// QKV fused: q,k f32; v bf16 directly.
__global__ __launch_bounds__(256) void k_mgemm_qkv(const unsigned short* __restrict__ A,
                                                   const unsigned short* __restrict__ wqt,
                                                   const unsigned short* __restrict__ wkt,
                                                   const unsigned short* __restrict__ wvt,
                                                   float* __restrict__ q,
                                                   float* __restrict__ k,
                                                   unsigned short* __restrict__ v) {
    int nt = blockIdx.x;
    if (nt < 8)       mgemm_core<0>(A, wqt, q, 1024, 1024, blockIdx.y * 128, nt * 128);
    else if (nt < 12) mgemm_core<0>(A, wkt, k, 512, 1024, blockIdx.y * 128, (nt - 8) * 128);
    else              mgemm_core<2>(A, wvt, v, 512, 1024, blockIdx.y * 128, (nt - 12) * 128);
}

__global__ __launch_bounds__(256) void k_mgemm_gu(const unsigned short* __restrict__ A,
                                                  const unsigned short* __restrict__ wgt,
                                                  const unsigned short* __restrict__ wut,
                                                  unsigned short* __restrict__ g,
                                                  unsigned short* __restrict__ u) {
    int nt = blockIdx.x;
    const unsigned short* Bt = (nt < 24) ? wgt : wut;
    unsigned short* C = (nt < 24) ? g : u;
    int bn = (nt < 24 ? nt : nt - 24) * 128;
    mgemm_core<2>(A, Bt, C, 3072, 1024, blockIdx.y * 128, bn);
}

// ---------------------------------------------------------------------------
// Per-head RMSNorm + RoPE, f32 in -> bf16 out.
__global__ __launch_bounds__(256) void k_qknorm_rope(const float* __restrict__ qk,
                                                     unsigned short* __restrict__ out,
                                                     const float* __restrict__ nw,
                                                     int nheads) {
    int tid = threadIdx.x;
    int w = tid >> 6, lane = tid & 63;
    int gid = blockIdx.x * 4 + w;
    int row = gid / nheads;
    int pos = row & (SS - 1);
    size_t base = (size_t)gid * HD;
    float xv = qk[base + lane];
    float ss = xv * xv;
#pragma unroll
    for (int off = 1; off < 64; off <<= 1) ss += __shfl_xor(ss, off);
    float scale = rsqrtf(ss * (1.0f / HD) + 1e-6f);
    float xn = xv * scale * nw[lane];
    int j = lane & 31;
    float inv_freq = powf(1.0e6f, -(float)j * (1.0f / 32.0f));
    float f = (float)pos * inv_freq;
    float c = cosf(f), s = sinf(f);
    float partner = __shfl_xor(xn, 32);
    float rot = (lane < 32) ? -partner : partner;
    out[base + lane] = f2bf(xn * c + rot * s);
}

// ---------------------------------------------------------------------------
// MFMA flash attention. Block = 128 q-rows x 1 head, 4 waves x 32 q. KVBLK=64.
// S^T = mfma32(K, Q)  (lane owns q = lane&31; keys per reg: (r&3)+8*(r>>2)+4*h)
// O^T = mfma32(V^T, P^T); V^T reg-staged into pad-70 LDS; K via global_load_lds
// with XOR-swizzled source + swizzled ds_read_b128 (both-sides involution).
__global__ __launch_bounds__(256) void k_mattn(const unsigned short* __restrict__ q,
                                               const unsigned short* __restrict__ k,
                                               const unsigned short* __restrict__ v,
                                               const int* __restrict__ amask,
                                               unsigned short* __restrict__ out,
                                               int sliding) {
    __shared__ __align__(16) char smem[18432];
    unsigned short* Klds = (unsigned short*)smem;            // [64][64] bf16, swizzled
    unsigned int*   VtU  = (unsigned int*)(smem + 8192);     // V^T [64 d][stride 70 u16]
    float* mlds          = (float*)(smem + 17152);           // [64] pad mask
    unsigned short* Olds = (unsigned short*)smem;            // overlay after loop

    const int b = blockIdx.z, head = blockIdx.y, q0 = blockIdx.x * 128;
    const int kvh = head >> 1;
    const int tid = threadIdx.x, w = tid >> 6, lane = tid & 63;
    const int h = lane >> 5, ln31 = lane & 31;
    const int qg = q0 + w * 32 + ln31;
    const float sscale = 0.125f;

    // Q fragments (B-operand): col=q=lane&31, kdim d = 16c + 8h + {0..7}
    bf16x8 qf[4];
    const unsigned short* qrow = q + (size_t)(b * SS + qg) * 1024 + head * 64;
#pragma unroll
    for (int c = 0; c < 4; ++c) qf[c] = *(const bf16x8*)(qrow + c * 16 + h * 8);

    f32x16 O0 = {}, O1 = {};
    float m = -3.4e38f, l_sum = 0.0f;

    int t_lo = 0, t_hi = (SS >> 6) - 1;
    if (sliding) {
        int lo = q0 - WW; if (lo < 0) lo = 0;
        int hi = q0 + 127 + WW; if (hi > SS - 1) hi = SS - 1;
        t_lo = lo >> 6; t_hi = hi >> 6;
    }

    const int vd = tid & 63, vw = tid >> 6;   // V-transpose mapping

    for (int t = t_lo; t <= t_hi; ++t) {
        int kv0 = t << 6;
        __syncthreads();
        if (tid < 64) mlds[tid] = amask[b * SS + kv0 + tid] ? 0.0f : NEG_INF;
        // K stage: linear LDS dest, inverse-swizzled global source
#pragma unroll
        for (int i = 0; i < 2; ++i) {
            int slot = i * 256 + w * 64 + lane;
            int row = slot >> 3, u = slot & 7;
            int ug = u ^ (row & 7);
            const unsigned short* src = k + (size_t)(b * SS + kv0 + row) * 512 + kvh * 64 + ug * 8;
            gll16(src, Klds + (size_t)slot * 8);
        }
        // V stage: transpose into VtU (pad 70 -> u32 stride 35)
        {
            const unsigned short* vsrc = v + (size_t)(b * SS + kv0 + vw * 16) * 512 + kvh * 64 + vd;
            unsigned short tmp[16];
#pragma unroll
            for (int kk = 0; kk < 16; ++kk) tmp[kk] = vsrc[(size_t)kk * 512];
#pragma unroll
            for (int j = 0; j < 8; ++j)
                VtU[vd * 35 + vw * 8 + j] =
                    (unsigned int)tmp[2 * j] | ((unsigned int)tmp[2 * j + 1] << 16);
        }
        __syncthreads();

        // QK^T: S^T subtiles (keys 0..31, 32..63)
        f32x16 a0 = {}, a1 = {};
#pragma unroll
        for (int c = 0; c < 4; ++c) {
            int u = (2 * c + h) ^ (ln31 & 7);
            bf16x8 k0 = *(const bf16x8*)&Klds[ln31 * 64 + u * 8];
            bf16x8 k1 = *(const bf16x8*)&Klds[(32 + ln31) * 64 + u * 8];
            a0 = __builtin_amdgcn_mfma_f32_32x32x16_bf16(k0, qf[c], a0, 0, 0, 0);
            a1 = __builtin_amdgcn_mfma_f32_32x32x16_bf16(k1, qf[c], a1, 0, 0, 0);
        }

        // softmax (f32, online)
        float tmax = -3.4e38f;
#pragma unroll
        for (int r = 0; r < 16; ++r) {
            int kl = (r & 3) + 8 * (r >> 2) + 4 * h;
            float mv0 = mlds[kl], mv1 = mlds[32 + kl];
            if (sliding) {
                int d0 = qg - (kv0 + kl); if (d0 < 0) d0 = -d0;
                int d1 = qg - (kv0 + 32 + kl); if (d1 < 0) d1 = -d1;
                if (d0 > WW) mv0 = NEG_INF;
                if (d1 > WW) mv1 = NEG_INF;
            }
            a0[r] = a0[r] * sscale + mv0;
            a1[r] = a1[r] * sscale + mv1;
            tmax = fmaxf(tmax, fmaxf(a0[r], a1[r]));
        }
        tmax = fmaxf(tmax, __shfl_xor(tmax, 32));
        float nm = fmaxf(m, tmax);
        float corr = __expf(m - nm);
        float tsum = 0.0f;
#pragma unroll
        for (int r = 0; r < 16; ++r) {
            a0[r] = __expf(a0[r] - nm);
            a1[r] = __expf(a1[r] - nm);
            tsum += a0[r] + a1[r];
        }
        tsum += __shfl_xor(tsum, 32);
        l_sum = l_sum * corr + tsum;
#pragma unroll
        for (int r = 0; r < 16; ++r) { O0[r] *= corr; O1[r] *= corr; }
        m = nm;

        // PV: O^T += mfma(Vt, P^T)
#pragma unroll
        for (int s = 0; s < 2; ++s) {
#pragma unroll
            for (int c2 = 0; c2 < 2; ++c2) {
                float p0v = s ? a1[8 * c2 + 0] : a0[8 * c2 + 0];
                float p1v = s ? a1[8 * c2 + 1] : a0[8 * c2 + 1];
                float p2v = s ? a1[8 * c2 + 2] : a0[8 * c2 + 2];
                float p3v = s ? a1[8 * c2 + 3] : a0[8 * c2 + 3];
                float p4v = s ? a1[8 * c2 + 4] : a0[8 * c2 + 4];
                float p5v = s ? a1[8 * c2 + 5] : a0[8 * c2 + 5];
                float p6v = s ? a1[8 * c2 + 6] : a0[8 * c2 + 6];
                float p7v = s ? a1[8 * c2 + 7] : a0[8 * c2 + 7];
                unsigned int A0 = pkbf(p0v, p1v);
                unsigned int A1 = pkbf(p2v, p3v);
                unsigned int A2 = pkbf(p4v, p5v);
                unsigned int A3 = pkbf(p6v, p7v);
                unsigned int pA0 = (unsigned int)__shfl_xor((int)A0, 32);
                unsigned int pA1 = (unsigned int)__shfl_xor((int)A1, 32);
                unsigned int pA2 = (unsigned int)__shfl_xor((int)A2, 32);
                unsigned int pA3 = (unsigned int)__shfl_xor((int)A3, 32);
                union { unsigned int u[4]; bf16x8 v; } pf;
                pf.u[0] = h ? pA2 : A0;
                pf.u[1] = h ? pA3 : A1;
                pf.u[2] = h ? A2 : pA0;
                pf.u[3] = h ? A3 : pA1;
#pragma unroll
                for (int dt = 0; dt < 2; ++dt) {
                    int base = (dt * 32 + ln31) * 35 + s * 16 + c2 * 8 + h * 4;
                    union { unsigned int u[4]; bf16x8 v; } vf;
                    vf.u[0] = VtU[base + 0];
                    vf.u[1] = VtU[base + 1];
                    vf.u[2] = VtU[base + 2];
                    vf.u[3] = VtU[base + 3];
                    if (dt == 0) O0 = __builtin_amdgcn_mfma_f32_32x32x16_bf16(vf.v, pf.v, O0, 0, 0, 0);
                    else         O1 = __builtin_amdgcn_mfma_f32_32x32x16_bf16(vf.v, pf.v, O1, 0, 0, 0);
                }
            }
        }
    }

    // epilogue: transpose O^T -> O via per-wave LDS region, store bf16
    __syncthreads();
    float rl = 1.0f / l_sum;
    unsigned short* myO = Olds + w * 2240;   // [32 q][stride 70]
#pragma unroll
    for (int dt = 0; dt < 2; ++dt)
#pragma unroll
        for (int r = 0; r < 16; ++r) {
            int d = dt * 32 + (r & 3) + 8 * (r >> 2) + 4 * h;
            float val = (dt ? O1[r] : O0[r]) * rl;
            myO[ln31 * 70 + d] = f2bf(val);
        }
    int qr = lane >> 1, half = lane & 1;
    const unsigned int* osrc = (const unsigned int*)Olds + (size_t)w * 1120 + qr * 35 + half * 16;
    unsigned int vals[16];
#pragma unroll
    for (int j = 0; j < 16; ++j) vals[j] = osrc[j];
    unsigned short* dst = out + (size_t)(b * SS + q0 + w * 32 + qr) * 1024 + head * 64 + half * 32;
#pragma unroll
    for (int j = 0; j < 4; ++j)
        ((uint4*)dst)[j] = make_uint4(vals[4 * j], vals[4 * j + 1], vals[4 * j + 2], vals[4 * j + 3]);
}

// ---------------------------------------------------------------------------
__global__ __launch_bounds__(256) void k_silu_bf16(unsigned short* __restrict__ g,
                                                   const unsigned short* __restrict__ u) {
    int i = blockIdx.x * 256 + threadIdx.x;
    u16x8 gv = ((const u16x8*)g)[i];
    u16x8 uv = ((const u16x8*)u)[i];
    u16x8 o;
#pragma unroll
    for (int j = 0; j < 8; ++j) {
        float gf = bf2f(gv[j]), uf = bf2f(uv[j]);
        o[j] = f2bf(gf / (1.0f + __expf(-gf)) * uf);
    }
    ((u16x8*)g)[i] = o;
}

// ---------------------------------------------------------------------------
extern "C" void kernel_launch(void* const* d_in, const int* in_sizes, int n_in,
                              void* d_out, int out_size, void* d_ws, size_t ws_size,
                              hipStream_t stream) {
    const int* input_ids = (const int*)d_in[0];
    const int* amask     = (const int*)d_in[1];
    const float* embed   = (const float*)d_in[2];
    const float* wq      = (const float*)d_in[3];
    const float* wk      = (const float*)d_in[4];
    const float* wv      = (const float*)d_in[5];
    const float* wo      = (const float*)d_in[6];
    const float* qnw     = (const float*)d_in[7];
    const float* knw     = (const float*)d_in[8];
    const float* ln1     = (const float*)d_in[9];
    const float* ln2     = (const float*)d_in[10];
    const float* wg      = (const float*)d_in[11];
    const float* wu      = (const float*)d_in[12];
    const float* wd      = (const float*)d_in[13];
    const float* fnorm   = (const float*)d_in[14];
    float* out = (float*)d_out;

    const int ROWS = BB * SS;  // 4096
    float* h  = (float*)d_ws;                          // [4096,1024] f32
    float* qb = h + (size_t)ROWS * HH;                 // [4096,1024] f32
    float* kb = qb + (size_t)ROWS * HH;                // [4096,512]  f32
    unsigned short* xb  = (unsigned short*)(kb + (size_t)ROWS * (NKV * HD)); // [4096,1024]
    unsigned short* qbf = xb + (size_t)ROWS * HH;           // [4096,1024]
    unsigned short* kbf = qbf + (size_t)ROWS * HH;          // [4096,512]
    unsigned short* vbf = kbf + (size_t)ROWS * (NKV * HD);  // [4096,512]
    unsigned short* gbf = vbf + (size_t)ROWS * (NKV * HD);  // [4096,3072]
    unsigned short* ubf = gbf + (size_t)ROWS * FF;          // [4096,3072]
    unsigned short* wbf = ubf + (size_t)ROWS * FF;          // 12.58M

    const size_t OQ = 0, OK_ = 1048576, OV = 1572864, OO = 2097152,
                 OG = 3145728, OU = 6291456, OD = 9437184;

    k_embed<<<ROWS, 256, 0, stream>>>(input_ids, embed, h);

    for (int l = 0; l < LL; ++l) {
        const float* wq_l = wq + (size_t)l * HH * (NHH * HD);
        const float* wk_l = wk + (size_t)l * HH * (NKV * HD);
        const float* wv_l = wv + (size_t)l * HH * (NKV * HD);
        const float* wo_l = wo + (size_t)l * (NHH * HD) * HH;
        const float* wg_l = wg + (size_t)l * HH * FF;
        const float* wu_l = wu + (size_t)l * HH * FF;
        const float* wd_l = wd + (size_t)l * FF * HH;

        k_cast_t<<<dim3(16, 16), 256, 0, stream>>>(wq_l, wbf + OQ, 1024, 1024);
        k_cast_t<<<dim3(8, 16),  256, 0, stream>>>(wk_l, wbf + OK_, 512, 1024);
        k_cast_t<<<dim3(8, 16),  256, 0, stream>>>(wv_l, wbf + OV, 512, 1024);
        k_cast_t<<<dim3(16, 16), 256, 0, stream>>>(wo_l, wbf + OO, 1024, 1024);
        k_cast_t<<<dim3(48, 16), 256, 0, stream>>>(wg_l, wbf + OG, 3072, 1024);
        k_cast_t<<<dim3(48, 16), 256, 0, stream>>>(wu_l, wbf + OU, 3072, 1024);
        k_cast_t<<<dim3(16, 48), 256, 0, stream>>>(wd_l, wbf + OD, 1024, 3072);

        k_rms_bf16<<<ROWS, 256, 0, stream>>>(h, ln1 + l * HH, xb);

        k_mgemm_qkv<<<dim3(16, 32), 256, 0, stream>>>(xb, wbf + OQ, wbf + OK_, wbf + OV,
                                                      qb, kb, vbf);

        k_qknorm_rope<<<ROWS * NHH / 4, 256, 0, stream>>>(qb, qbf, qnw + l * HD, NHH);
        k_qknorm_rope<<<ROWS * NKV / 4, 256, 0, stream>>>(kb, kbf, knw + l * HD, NKV);

        k_mattn<<<dim3(SS / 128, NHH, BB), 256, 0, stream>>>(qbf, kbf, vbf, amask, xb, l & 1);

        k_mgemm<1><<<dim3(8, 32), 256, 0, stream>>>(xb, wbf + OO, h, 1024, 1024);

        k_rms_bf16<<<ROWS, 256, 0, stream>>>(h, ln2 + l * HH, xb);

        k_mgemm_gu<<<dim3(48, 32), 256, 0, stream>>>(xb, wbf + OG, wbf + OU, gbf, ubf);

        k_silu_bf16<<<ROWS * FF / 8 / 256, 256, 0, stream>>>(gbf, ubf);

        k_mgemm<1><<<dim3(8, 32), 256, 0, stream>>>(gbf, wbf + OD, h, 1024, 3072);
    }

    k_rms<<<ROWS, 256, 0, stream>>>(h, fnorm, out);
}

// Round 5
// 1411.673 us; speedup vs baseline: 5.7630x; 1.1127x over previous
//
#include <hip/hip_runtime.h>
#include <math.h>

#define BB 4
#define SS 1024
#define HH 1024
#define LL 4
#define NHH 16
#define NKV 8
#define HD 64
#define FF 3072
#define WW 12
#define NEG_INF (-1e9f)

// wbf (bf16 weight^T buffer) element offsets
#define OQ  0
#define OK_ 1048576
#define OV  1572864
#define OO  2097152
#define OG  3145728
#define OU  6291456
#define OD  9437184

typedef __attribute__((ext_vector_type(8))) short bf16x8;
typedef __attribute__((ext_vector_type(4))) float f32x4;
typedef __attribute__((ext_vector_type(16))) float f32x16;
typedef __attribute__((ext_vector_type(8))) unsigned short u16x8;

__device__ __forceinline__ unsigned short f2bf(float f) {
    union { float f; unsigned int u; } v; v.f = f;
    unsigned int r = (v.u + 0x7fffu + ((v.u >> 16) & 1u)) >> 16;
    return (unsigned short)r;
}
__device__ __forceinline__ float bf2f(unsigned short u) {
    union { unsigned int u; float f; } v; v.u = ((unsigned int)u) << 16;
    return v.f;
}
__device__ __forceinline__ unsigned int pkbf(float lo, float hi) {
    return (unsigned int)f2bf(lo) | ((unsigned int)f2bf(hi) << 16);
}
__device__ __forceinline__ void gll16(const void* g, void* l) {
    __builtin_amdgcn_global_load_lds((const __attribute__((address_space(1))) void*)g,
                                     (__attribute__((address_space(3))) void*)l, 16, 0, 0);
}

// ---------------------------------------------------------------------------
__global__ __launch_bounds__(256) void k_embed(const int* __restrict__ ids,
                                               const float* __restrict__ embed,
                                               float* __restrict__ h) {
    int row = blockIdx.x, tid = threadIdx.x;
    int id = ids[row];
    ((float4*)(h + (size_t)row * HH))[tid] = ((const float4*)(embed + (size_t)id * HH))[tid];
}

// ---------------------------------------------------------------------------
__global__ __launch_bounds__(256) void k_rms_bf16(const float* __restrict__ in,
                                                  const float* __restrict__ w,
                                                  unsigned short* __restrict__ out) {
    __shared__ float red[4];
    int row = blockIdx.x, tid = threadIdx.x;
    float4 v = ((const float4*)(in + (size_t)row * HH))[tid];
    float ss = v.x * v.x + v.y * v.y + v.z * v.z + v.w * v.w;
#pragma unroll
    for (int off = 1; off < 64; off <<= 1) ss += __shfl_xor(ss, off);
    if ((tid & 63) == 0) red[tid >> 6] = ss;
    __syncthreads();
    float tot = red[0] + red[1] + red[2] + red[3];
    float scale = rsqrtf(tot * (1.0f / HH) + 1e-6f);
    float4 wv = ((const float4*)w)[tid];
    ushort4 o;
    o.x = f2bf(v.x * scale * wv.x); o.y = f2bf(v.y * scale * wv.y);
    o.z = f2bf(v.z * scale * wv.z); o.w = f2bf(v.w * scale * wv.w);
    *(ushort4*)&out[(size_t)row * HH + tid * 4] = o;
}

// ---------------------------------------------------------------------------
// Fused: h += p0(+p1(+p2)); then RMSNorm(h)*w -> outx (bf16 or f32).
template <int NP, int BF16OUT>
__global__ __launch_bounds__(256) void k_rms_add(float* __restrict__ h,
                                                 const float* __restrict__ p0,
                                                 const float* __restrict__ p1,
                                                 const float* __restrict__ p2,
                                                 const float* __restrict__ w,
                                                 void* __restrict__ outx) {
    __shared__ float red[4];
    int row = blockIdx.x, tid = threadIdx.x;
    size_t base = (size_t)row * HH;
    float4 v = ((const float4*)(h + base))[tid];
    float4 a = ((const float4*)(p0 + base))[tid];
    v.x += a.x; v.y += a.y; v.z += a.z; v.w += a.w;
    if (NP > 1) {
        float4 b = ((const float4*)(p1 + base))[tid];
        v.x += b.x; v.y += b.y; v.z += b.z; v.w += b.w;
    }
    if (NP > 2) {
        float4 c = ((const float4*)(p2 + base))[tid];
        v.x += c.x; v.y += c.y; v.z += c.z; v.w += c.w;
    }
    ((float4*)(h + base))[tid] = v;
    float ss = v.x * v.x + v.y * v.y + v.z * v.z + v.w * v.w;
#pragma unroll
    for (int off = 1; off < 64; off <<= 1) ss += __shfl_xor(ss, off);
    if ((tid & 63) == 0) red[tid >> 6] = ss;
    __syncthreads();
    float tot = red[0] + red[1] + red[2] + red[3];
    float scale = rsqrtf(tot * (1.0f / HH) + 1e-6f);
    float4 wv = ((const float4*)w)[tid];
    float rx = v.x * scale * wv.x, ry = v.y * scale * wv.y;
    float rz = v.z * scale * wv.z, rw = v.w * scale * wv.w;
    if (BF16OUT) {
        ushort4 o;
        o.x = f2bf(rx); o.y = f2bf(ry); o.z = f2bf(rz); o.w = f2bf(rw);
        *(ushort4*)&((unsigned short*)outx)[base + tid * 4] = o;
    } else {
        float4 o; o.x = rx; o.y = ry; o.z = rz; o.w = rw;
        ((float4*)((float*)outx + base))[tid] = o;
    }
}

// ---------------------------------------------------------------------------
// All 7 weight cast+transposes for one layer in one dispatch (3072 tiles).
__global__ __launch_bounds__(256) void k_cast_all(const float* __restrict__ wq,
                                                  const float* __restrict__ wk,
                                                  const float* __restrict__ wv,
                                                  const float* __restrict__ wo,
                                                  const float* __restrict__ wg,
                                                  const float* __restrict__ wu,
                                                  const float* __restrict__ wd,
                                                  unsigned short* __restrict__ wbf) {
    __shared__ float t[64][65];
    int tI = blockIdx.x;
    const float* W; unsigned short* Wt; int N, K, local;
    if (tI < 256)       { W = wq; Wt = wbf + OQ;  N = 1024; K = 1024; local = tI; }
    else if (tI < 384)  { W = wk; Wt = wbf + OK_; N = 512;  K = 1024; local = tI - 256; }
    else if (tI < 512)  { W = wv; Wt = wbf + OV;  N = 512;  K = 1024; local = tI - 384; }
    else if (tI < 768)  { W = wo; Wt = wbf + OO;  N = 1024; K = 1024; local = tI - 512; }
    else if (tI < 1536) { W = wg; Wt = wbf + OG;  N = 3072; K = 1024; local = tI - 768; }
    else if (tI < 2304) { W = wu; Wt = wbf + OU;  N = 3072; K = 1024; local = tI - 1536; }
    else                { W = wd; Wt = wbf + OD;  N = 1024; K = 3072; local = tI - 2304; }
    int tn = N >> 6;
    int n0 = (local % tn) * 64, k0 = (local / tn) * 64;
    int tid = threadIdx.x;
    int r = tid >> 4;
    int c4 = (tid & 15) * 4;
#pragma unroll
    for (int e = 0; e < 4; ++e) {
        int kk = r + e * 16;
        float4 vv = *(const float4*)&W[(size_t)(k0 + kk) * N + n0 + c4];
        t[c4 + 0][kk] = vv.x;
        t[c4 + 1][kk] = vv.y;
        t[c4 + 2][kk] = vv.z;
        t[c4 + 3][kk] = vv.w;
    }
    __syncthreads();
#pragma unroll
    for (int e = 0; e < 4; ++e) {
        int nn = r + e * 16;
        ushort4 o;
        o.x = f2bf(t[nn][c4 + 0]);
        o.y = f2bf(t[nn][c4 + 1]);
        o.z = f2bf(t[nn][c4 + 2]);
        o.w = f2bf(t[nn][c4 + 3]);
        *(ushort4*)&Wt[(size_t)(n0 + nn) * K + k0 + c4] = o;
    }
}

// ---------------------------------------------------------------------------
// bf16 MFMA GEMM core. EPI: 0 = store f32, 1 = += f32, 2 = store bf16.
// A strided lda, Bt strided ldb; iterates k in [0,K).
template <int EPI>
__device__ __forceinline__ void mgemm_core(const unsigned short* __restrict__ A,
                                           const unsigned short* __restrict__ Bt,
                                           void* __restrict__ Cv,
                                           int N, int K, int lda, int ldb,
                                           int bm, int bn) {
    __shared__ unsigned short As[128 * 32];
    __shared__ unsigned short Bs[128 * 32];
    int tid = threadIdx.x;
    int w = tid >> 6, l = tid & 63;
    int wr = (w >> 1) * 64, wc = (w & 1) * 64;

    f32x4 acc[4][4] = {};

    for (int k0 = 0; k0 < K; k0 += 32) {
        __syncthreads();
#pragma unroll
        for (int i = 0; i < 2; ++i) {
            int cb = i * 256 + w * 64;
            int c = cb + l;
            const unsigned short* ga = A + (size_t)(bm + (c >> 2)) * lda + k0 + (c & 3) * 8;
            const unsigned short* gb = Bt + (size_t)(bn + (c >> 2)) * ldb + k0 + (c & 3) * 8;
            gll16(ga, As + cb * 8);
            gll16(gb, Bs + cb * 8);
        }
        __syncthreads();

        bf16x8 af[4], bfr[4];
#pragma unroll
        for (int i = 0; i < 4; ++i) {
            int m = wr + i * 16 + (l & 15);
            af[i] = *(const bf16x8*)&As[m * 32 + (l >> 4) * 8];
            int n = wc + i * 16 + (l & 15);
            bfr[i] = *(const bf16x8*)&Bs[n * 32 + (l >> 4) * 8];
        }
#pragma unroll
        for (int i = 0; i < 4; ++i)
#pragma unroll
            for (int j = 0; j < 4; ++j)
                acc[i][j] = __builtin_amdgcn_mfma_f32_16x16x32_bf16(af[i], bfr[j], acc[i][j], 0, 0, 0);
    }

#pragma unroll
    for (int i = 0; i < 4; ++i) {
        int rbase = bm + wr + i * 16 + (l >> 4) * 4;
#pragma unroll
        for (int j = 0; j < 4; ++j) {
            int col = bn + wc + j * 16 + (l & 15);
#pragma unroll
            for (int r = 0; r < 4; ++r) {
                size_t off = (size_t)(rbase + r) * N + col;
                if (EPI == 0) ((float*)Cv)[off] = acc[i][j][r];
                else if (EPI == 1) ((float*)Cv)[off] += acc[i][j][r];
                else ((unsigned short*)Cv)[off] = f2bf(acc[i][j][r]);
            }
        }
    }
}

// Split-K GEMM: blockIdx.z = part; partial f32 -> p0/p1/p2.
template <int PARTS>
__global__ __launch_bounds__(256) void k_mgemm_splitk(const unsigned short* __restrict__ A,
                                                      const unsigned short* __restrict__ Bt,
                                                      float* __restrict__ p0,
                                                      float* __restrict__ p1,
                                                      float* __restrict__ p2,
                                                      int N, int Ktot) {
    int part = blockIdx.z;
    int Kp = Ktot / PARTS;
    float* C = (part == 0) ? p0 : (part == 1 ? p1 : p2);
    mgemm_core<0>(A + part * Kp, Bt + part * Kp, C, N, Kp, Ktot, Ktot,
                  blockIdx.y * 128, blockIdx.x * 128);
}

// QKV fused: q,k f32; v bf16 directly.
__global__ __launch_bounds__(256) void k_mgemm_qkv(const unsigned short* __restrict__ A,
                                                   const unsigned short* __restrict__ wqt,
                                                   const unsigned short* __restrict__ wkt,
                                                   const unsigned short* __restrict__ wvt,
                                                   float* __restrict__ q,
                                                   float* __restrict__ k,
                                                   unsigned short* __restrict__ v) {
    int nt = blockIdx.x;
    if (nt < 8)       mgemm_core<0>(A, wqt, q, 1024, 1024, 1024, 1024, blockIdx.y * 128, nt * 128);
    else if (nt < 12) mgemm_core<0>(A, wkt, k, 512, 1024, 1024, 1024, blockIdx.y * 128, (nt - 8) * 128);
    else              mgemm_core<2>(A, wvt, v, 512, 1024, 1024, 1024, blockIdx.y * 128, (nt - 12) * 128);
}

__global__ __launch_bounds__(256) void k_mgemm_gu(const unsigned short* __restrict__ A,
                                                  const unsigned short* __restrict__ wgt,
                                                  const unsigned short* __restrict__ wut,
                                                  unsigned short* __restrict__ g,
                                                  unsigned short* __restrict__ u) {
    int nt = blockIdx.x;
    const unsigned short* Bt = (nt < 24) ? wgt : wut;
    unsigned short* C = (nt < 24) ? g : u;
    int bn = (nt < 24 ? nt : nt - 24) * 128;
    mgemm_core<2>(A, Bt, C, 3072, 1024, 1024, 1024, blockIdx.y * 128, bn);
}

// ---------------------------------------------------------------------------
// Per-head RMSNorm + RoPE, f32 in -> bf16 out.
__global__ __launch_bounds__(256) void k_qknorm_rope(const float* __restrict__ qk,
                                                     unsigned short* __restrict__ out,
                                                     const float* __restrict__ nw,
                                                     int nheads) {
    int tid = threadIdx.x;
    int w = tid >> 6, lane = tid & 63;
    int gid = blockIdx.x * 4 + w;
    int row = gid / nheads;
    int pos = row & (SS - 1);
    size_t base = (size_t)gid * HD;
    float xv = qk[base + lane];
    float ss = xv * xv;
#pragma unroll
    for (int off = 1; off < 64; off <<= 1) ss += __shfl_xor(ss, off);
    float scale = rsqrtf(ss * (1.0f / HD) + 1e-6f);
    float xn = xv * scale * nw[lane];
    int j = lane & 31;
    float inv_freq = powf(1.0e6f, -(float)j * (1.0f / 32.0f));
    float f = (float)pos * inv_freq;
    float c = cosf(f), s = sinf(f);
    float partner = __shfl_xor(xn, 32);
    float rot = (lane < 32) ? -partner : partner;
    out[base + lane] = f2bf(xn * c + rot * s);
}

// ---------------------------------------------------------------------------
// MFMA flash attention (unchanged from round 4).
__global__ __launch_bounds__(256) void k_mattn(const unsigned short* __restrict__ q,
                                               const unsigned short* __restrict__ k,
                                               const unsigned short* __restrict__ v,
                                               const int* __restrict__ amask,
                                               unsigned short* __restrict__ out,
                                               int sliding) {
    __shared__ __align__(16) char smem[18432];
    unsigned short* Klds = (unsigned short*)smem;
    unsigned int*   VtU  = (unsigned int*)(smem + 8192);
    float* mlds          = (float*)(smem + 17152);
    unsigned short* Olds = (unsigned short*)smem;

    const int b = blockIdx.z, head = blockIdx.y, q0 = blockIdx.x * 128;
    const int kvh = head >> 1;
    const int tid = threadIdx.x, w = tid >> 6, lane = tid & 63;
    const int h = lane >> 5, ln31 = lane & 31;
    const int qg = q0 + w * 32 + ln31;
    const float sscale = 0.125f;

    bf16x8 qf[4];
    const unsigned short* qrow = q + (size_t)(b * SS + qg) * 1024 + head * 64;
#pragma unroll
    for (int c = 0; c < 4; ++c) qf[c] = *(const bf16x8*)(qrow + c * 16 + h * 8);

    f32x16 O0 = {}, O1 = {};
    float m = -3.4e38f, l_sum = 0.0f;

    int t_lo = 0, t_hi = (SS >> 6) - 1;
    if (sliding) {
        int lo = q0 - WW; if (lo < 0) lo = 0;
        int hi = q0 + 127 + WW; if (hi > SS - 1) hi = SS - 1;
        t_lo = lo >> 6; t_hi = hi >> 6;
    }

    const int vd = tid & 63, vw = tid >> 6;

    for (int t = t_lo; t <= t_hi; ++t) {
        int kv0 = t << 6;
        __syncthreads();
        if (tid < 64) mlds[tid] = amask[b * SS + kv0 + tid] ? 0.0f : NEG_INF;
#pragma unroll
        for (int i = 0; i < 2; ++i) {
            int slot = i * 256 + w * 64 + lane;
            int row = slot >> 3, u = slot & 7;
            int ug = u ^ (row & 7);
            const unsigned short* src = k + (size_t)(b * SS + kv0 + row) * 512 + kvh * 64 + ug * 8;
            gll16(src, Klds + (size_t)slot * 8);
        }
        {
            const unsigned short* vsrc = v + (size_t)(b * SS + kv0 + vw * 16) * 512 + kvh * 64 + vd;
            unsigned short tmp[16];
#pragma unroll
            for (int kk = 0; kk < 16; ++kk) tmp[kk] = vsrc[(size_t)kk * 512];
#pragma unroll
            for (int j = 0; j < 8; ++j)
                VtU[vd * 35 + vw * 8 + j] =
                    (unsigned int)tmp[2 * j] | ((unsigned int)tmp[2 * j + 1] << 16);
        }
        __syncthreads();

        f32x16 a0 = {}, a1 = {};
#pragma unroll
        for (int c = 0; c < 4; ++c) {
            int u = (2 * c + h) ^ (ln31 & 7);
            bf16x8 k0 = *(const bf16x8*)&Klds[ln31 * 64 + u * 8];
            bf16x8 k1 = *(const bf16x8*)&Klds[(32 + ln31) * 64 + u * 8];
            a0 = __builtin_amdgcn_mfma_f32_32x32x16_bf16(k0, qf[c], a0, 0, 0, 0);
            a1 = __builtin_amdgcn_mfma_f32_32x32x16_bf16(k1, qf[c], a1, 0, 0, 0);
        }

        float tmax = -3.4e38f;
#pragma unroll
        for (int r = 0; r < 16; ++r) {
            int kl = (r & 3) + 8 * (r >> 2) + 4 * h;
            float mv0 = mlds[kl], mv1 = mlds[32 + kl];
            if (sliding) {
                int d0 = qg - (kv0 + kl); if (d0 < 0) d0 = -d0;
                int d1 = qg - (kv0 + 32 + kl); if (d1 < 0) d1 = -d1;
                if (d0 > WW) mv0 = NEG_INF;
                if (d1 > WW) mv1 = NEG_INF;
            }
            a0[r] = a0[r] * sscale + mv0;
            a1[r] = a1[r] * sscale + mv1;
            tmax = fmaxf(tmax, fmaxf(a0[r], a1[r]));
        }
        tmax = fmaxf(tmax, __shfl_xor(tmax, 32));
        float nm = fmaxf(m, tmax);
        float corr = __expf(m - nm);
        float tsum = 0.0f;
#pragma unroll
        for (int r = 0; r < 16; ++r) {
            a0[r] = __expf(a0[r] - nm);
            a1[r] = __expf(a1[r] - nm);
            tsum += a0[r] + a1[r];
        }
        tsum += __shfl_xor(tsum, 32);
        l_sum = l_sum * corr + tsum;
#pragma unroll
        for (int r = 0; r < 16; ++r) { O0[r] *= corr; O1[r] *= corr; }
        m = nm;

#pragma unroll
        for (int s = 0; s < 2; ++s) {
#pragma unroll
            for (int c2 = 0; c2 < 2; ++c2) {
                float p0v = s ? a1[8 * c2 + 0] : a0[8 * c2 + 0];
                float p1v = s ? a1[8 * c2 + 1] : a0[8 * c2 + 1];
                float p2v = s ? a1[8 * c2 + 2] : a0[8 * c2 + 2];
                float p3v = s ? a1[8 * c2 + 3] : a0[8 * c2 + 3];
                float p4v = s ? a1[8 * c2 + 4] : a0[8 * c2 + 4];
                float p5v = s ? a1[8 * c2 + 5] : a0[8 * c2 + 5];
                float p6v = s ? a1[8 * c2 + 6] : a0[8 * c2 + 6];
                float p7v = s ? a1[8 * c2 + 7] : a0[8 * c2 + 7];
                unsigned int A0 = pkbf(p0v, p1v);
                unsigned int A1 = pkbf(p2v, p3v);
                unsigned int A2 = pkbf(p4v, p5v);
                unsigned int A3 = pkbf(p6v, p7v);
                unsigned int pA0 = (unsigned int)__shfl_xor((int)A0, 32);
                unsigned int pA1 = (unsigned int)__shfl_xor((int)A1, 32);
                unsigned int pA2 = (unsigned int)__shfl_xor((int)A2, 32);
                unsigned int pA3 = (unsigned int)__shfl_xor((int)A3, 32);
                union { unsigned int u[4]; bf16x8 v; } pf;
                pf.u[0] = h ? pA2 : A0;
                pf.u[1] = h ? pA3 : A1;
                pf.u[2] = h ? A2 : pA0;
                pf.u[3] = h ? A3 : pA1;
#pragma unroll
                for (int dt = 0; dt < 2; ++dt) {
                    int base = (dt * 32 + ln31) * 35 + s * 16 + c2 * 8 + h * 4;
                    union { unsigned int u[4]; bf16x8 v; } vf;
                    vf.u[0] = VtU[base + 0];
                    vf.u[1] = VtU[base + 1];
                    vf.u[2] = VtU[base + 2];
                    vf.u[3] = VtU[base + 3];
                    if (dt == 0) O0 = __builtin_amdgcn_mfma_f32_32x32x16_bf16(vf.v, pf.v, O0, 0, 0, 0);
                    else         O1 = __builtin_amdgcn_mfma_f32_32x32x16_bf16(vf.v, pf.v, O1, 0, 0, 0);
                }
            }
        }
    }

    __syncthreads();
    float rl = 1.0f / l_sum;
    unsigned short* myO = Olds + w * 2240;
#pragma unroll
    for (int dt = 0; dt < 2; ++dt)
#pragma unroll
        for (int r = 0; r < 16; ++r) {
            int d = dt * 32 + (r & 3) + 8 * (r >> 2) + 4 * h;
            float val = (dt ? O1[r] : O0[r]) * rl;
            myO[ln31 * 70 + d] = f2bf(val);
        }
    int qr = lane >> 1, half = lane & 1;
    const unsigned int* osrc = (const unsigned int*)Olds + (size_t)w * 1120 + qr * 35 + half * 16;
    unsigned int vals[16];
#pragma unroll
    for (int j = 0; j < 16; ++j) vals[j] = osrc[j];
    unsigned short* dst = out + (size_t)(b * SS + q0 + w * 32 + qr) * 1024 + head * 64 + half * 32;
#pragma unroll
    for (int j = 0; j < 4; ++j)
        ((uint4*)dst)[j] = make_uint4(vals[4 * j], vals[4 * j + 1], vals[4 * j + 2], vals[4 * j + 3]);
}

// ---------------------------------------------------------------------------
__global__ __launch_bounds__(256) void k_silu_bf16(unsigned short* __restrict__ g,
                                                   const unsigned short* __restrict__ u) {
    int i = blockIdx.x * 256 + threadIdx.x;
    u16x8 gv = ((const u16x8*)g)[i];
    u16x8 uv = ((const u16x8*)u)[i];
    u16x8 o;
#pragma unroll
    for (int j = 0; j < 8; ++j) {
        float gf = bf2f(gv[j]), uf = bf2f(uv[j]);
        o[j] = f2bf(gf / (1.0f + __expf(-gf)) * uf);
    }
    ((u16x8*)g)[i] = o;
}

// ---------------------------------------------------------------------------
extern "C" void kernel_launch(void* const* d_in, const int* in_sizes, int n_in,
                              void* d_out, int out_size, void* d_ws, size_t ws_size,
                              hipStream_t stream) {
    const int* input_ids = (const int*)d_in[0];
    const int* amask     = (const int*)d_in[1];
    const float* embed   = (const float*)d_in[2];
    const float* wq      = (const float*)d_in[3];
    const float* wk      = (const float*)d_in[4];
    const float* wv      = (const float*)d_in[5];
    const float* wo      = (const float*)d_in[6];
    const float* qnw     = (const float*)d_in[7];
    const float* knw     = (const float*)d_in[8];
    const float* ln1     = (const float*)d_in[9];
    const float* ln2     = (const float*)d_in[10];
    const float* wg      = (const float*)d_in[11];
    const float* wu      = (const float*)d_in[12];
    const float* wd      = (const float*)d_in[13];
    const float* fnorm   = (const float*)d_in[14];
    float* out = (float*)d_out;

    const int ROWS = BB * SS;  // 4096
    float* h  = (float*)d_ws;                          // [4096,1024] f32
    float* qb = h + (size_t)ROWS * HH;                 // [4096,1024] f32 (also splitk p0)
    float* kb = qb + (size_t)ROWS * HH;                // [4096,512]  f32
    unsigned short* xb  = (unsigned short*)(kb + (size_t)ROWS * (NKV * HD)); // [4096,1024]
    unsigned short* qbf = xb + (size_t)ROWS * HH;
    unsigned short* kbf = qbf + (size_t)ROWS * HH;
    unsigned short* vbf = kbf + (size_t)ROWS * (NKV * HD);
    unsigned short* gbf = vbf + (size_t)ROWS * (NKV * HD);  // [4096,3072] (also wo p1)
    unsigned short* ubf = gbf + (size_t)ROWS * FF;          // [4096,3072] (also wd p1)
    unsigned short* wbf = ubf + (size_t)ROWS * FF;          // 12.58M (head doubles as wd p2)

    k_embed<<<ROWS, 256, 0, stream>>>(input_ids, embed, h);
    k_rms_bf16<<<ROWS, 256, 0, stream>>>(h, ln1, xb);

    for (int l = 0; l < LL; ++l) {
        const float* wq_l = wq + (size_t)l * HH * (NHH * HD);
        const float* wk_l = wk + (size_t)l * HH * (NKV * HD);
        const float* wv_l = wv + (size_t)l * HH * (NKV * HD);
        const float* wo_l = wo + (size_t)l * (NHH * HD) * HH;
        const float* wg_l = wg + (size_t)l * HH * FF;
        const float* wu_l = wu + (size_t)l * HH * FF;
        const float* wd_l = wd + (size_t)l * FF * HH;

        k_cast_all<<<3072, 256, 0, stream>>>(wq_l, wk_l, wv_l, wo_l, wg_l, wu_l, wd_l, wbf);

        k_mgemm_qkv<<<dim3(16, 32), 256, 0, stream>>>(xb, wbf + OQ, wbf + OK_, wbf + OV,
                                                      qb, kb, vbf);

        k_qknorm_rope<<<ROWS * NHH / 4, 256, 0, stream>>>(qb, qbf, qnw + l * HD, NHH);
        k_qknorm_rope<<<ROWS * NKV / 4, 256, 0, stream>>>(kb, kbf, knw + l * HD, NKV);

        k_mattn<<<dim3(SS / 128, NHH, BB), 256, 0, stream>>>(qbf, kbf, vbf, amask, xb, l & 1);

        // wo: split-K=2 -> partials in qb, (float*)gbf; fused reduce + ln2-RMS.
        k_mgemm_splitk<2><<<dim3(8, 32, 2), 256, 0, stream>>>(xb, wbf + OO, qb, (float*)gbf,
                                                              nullptr, 1024, 1024);
        k_rms_add<2, 1><<<ROWS, 256, 0, stream>>>(h, qb, (float*)gbf, nullptr,
                                                  ln2 + l * HH, xb);

        k_mgemm_gu<<<dim3(48, 32), 256, 0, stream>>>(xb, wbf + OG, wbf + OU, gbf, ubf);

        k_silu_bf16<<<ROWS * FF / 8 / 256, 256, 0, stream>>>(gbf, ubf);

        // wd: split-K=3 -> partials in qb, (float*)ubf, (float*)wbf; fused reduce + next norm.
        k_mgemm_splitk<3><<<dim3(8, 32, 3), 256, 0, stream>>>(gbf, wbf + OD, qb, (float*)ubf,
                                                              (float*)wbf, 1024, 3072);
        if (l < LL - 1) {
            k_rms_add<3, 1><<<ROWS, 256, 0, stream>>>(h, qb, (float*)ubf, (float*)wbf,
                                                      ln1 + (l + 1) * HH, xb);
        } else {
            k_rms_add<3, 0><<<ROWS, 256, 0, stream>>>(h, qb, (float*)ubf, (float*)wbf,
                                                      fnorm, out);
        }
    }
}